// Round 1
// baseline (1380.050 us; speedup 1.0000x reference)
//
#include <hip/hip_runtime.h>

#define S_LEN 2048
#define NBH   32   // B*H = 2*16

typedef __attribute__((ext_vector_type(8))) __bf16 bf16x8;
typedef __attribute__((ext_vector_type(4))) float  f32x4;

// ---------------------------------------------------------------------------
// prep_k: K fp32 -> (kh, kl) bf16 hi/lo, fragment layout:
//   element (bh, key, d): dc=d>>5, g=(d>>3)&3, j=d&7
//   off = ((bh*2+dc)*2048 + key)*32 + g*8 + j
// B-fragment load (tile k0, lane l, dchunk dc) is then 16B contiguous:
//   off = ((bh*2+dc)*2048 + k0 + (l&15))*32 + (l>>4)*8
// ---------------------------------------------------------------------------
__global__ __launch_bounds__(256) void prep_k(const float* __restrict__ K,
                                              __bf16* __restrict__ kh,
                                              __bf16* __restrict__ kl) {
    const int total = NBH * S_LEN * 64;
    for (int idx = blockIdx.x * 256 + threadIdx.x; idx < total;
         idx += gridDim.x * 256) {
        int d   = idx & 63;
        int key = (idx >> 6) & (S_LEN - 1);
        int bh  = idx >> 17;
        float f = K[idx];
        __bf16 h  = (__bf16)f;
        __bf16 lo = (__bf16)(f - (float)h);
        int dc = d >> 5, g = (d >> 3) & 3, j = d & 7;
        size_t off = ((size_t)((bh * 2 + dc) * S_LEN + key) << 5) + g * 8 + j;
        kh[off] = h;
        kl[off] = lo;
    }
}

// ---------------------------------------------------------------------------
// prep_v: V fp32 -> vb bf16, transposed fragment layout:
//   element (bh, k, n): kc=k>>5, g=(k>>3)&3, j=k&7
//   off = ((bh*64+n)*64 + kc)*32 + g*8 + j
// PV B-fragment load (chunk c, n-tile n0, lane l) is 16B contiguous:
//   off = ((bh*64 + n0 + (l&15))*2048) + c*32 + (l>>4)*8
// ---------------------------------------------------------------------------
__global__ __launch_bounds__(256) void prep_v(const float* __restrict__ V,
                                              __bf16* __restrict__ vb) {
    const int total = NBH * S_LEN * 64;
    for (int idx = blockIdx.x * 256 + threadIdx.x; idx < total;
         idx += gridDim.x * 256) {
        int n  = idx & 63;
        int k  = (idx >> 6) & (S_LEN - 1);
        int bh = idx >> 17;
        float f = V[idx];
        int kc = k >> 5, g = (k >> 3) & 3, j = k & 7;
        size_t off = ((size_t)((bh * 64 + n) * 64 + kc) << 5) + g * 8 + j;
        vb[off] = (__bf16)f;
    }
}

// ---------------------------------------------------------------------------
// Main attention kernel. One block = one (bh, 16-row q tile). 512 thr, 8 waves.
//
// LDS f32 map (total 36128 f32 = 144512 B):
//   [0, 32768)      scores/e in fragment layout:
//                   (row,col): c=col>>5, gc=(col>>3)&3, j=col&7
//                   lane' = (gc<<4)|((row&3)<<2)|(row>>2)
//                   idx = c*512 + lane'*8 + j
//   [32768, 33792)  qfrag: [2 prec][2 dc][64 lane][8] bf16
//   [33792, 33920)  pmax[8][16]
//   [33920, 34048)  psum[8][16]
//   [34048, 34064)  mrow[16]
//   [34064, 34080)  rinv[16]
//   [34080, 36128)  partials[8][16][16]
// ---------------------------------------------------------------------------
__global__ __launch_bounds__(512) void attn_kernel(
    const float* __restrict__ Q, const int* __restrict__ mask,
    const __bf16* __restrict__ kh, const __bf16* __restrict__ kl,
    const __bf16* __restrict__ vb,
    float* __restrict__ ctxOut, float* __restrict__ scoresOut)
{
    extern __shared__ float lds[];
    __bf16* qf   = (__bf16*)(lds + 32768);
    float*  pmax = lds + 33792;
    float*  psum = lds + 33920;
    float*  mrow = lds + 34048;
    float*  rinv = lds + 34064;
    float*  parts= lds + 34080;

    const int t   = threadIdx.x;
    const int w   = t >> 6;
    const int l   = t & 63;
    const int l15 = l & 15;
    const int lg  = l >> 4;
    const int bh  = blockIdx.y;
    const int q0  = blockIdx.x << 4;

    // fragment-layout lane index for accessing (row=l15, kgroup=lg) patterns
    const int alane = (lg << 4) | ((l15 & 3) << 2) | (l15 >> 2);

    // ---- P0: stage Q*scale as hi/lo bf16 A-fragments -----------------------
    {
        const float* Qg = Q + ((size_t)bh * S_LEN + q0) * 64;
        for (int e = t; e < 16 * 64; e += 512) {
            int row = e >> 6, d = e & 63;
            float fs = Qg[e] * 0.125f;                 // fold 1/sqrt(64)
            __bf16 h  = (__bf16)fs;
            __bf16 lo = (__bf16)(fs - (float)h);
            int dc = d >> 5, g = (d >> 3) & 3, j = d & 7;
            int lane2 = (g << 4) | row;
            qf[((0 + dc) * 64 + lane2) * 8 + j] = h;   // prec 0: dc in {0,1}
            qf[((2 + dc) * 64 + lane2) * 8 + j] = lo;  // prec 1
        }
    }
    __syncthreads();

    // ---- P1: QK^T via split bf16 MFMA, store raw scores to LDS -------------
    {
        bf16x8 ah0 = *(bf16x8*)&qf[(0 * 64 + l) * 8];
        bf16x8 ah1 = *(bf16x8*)&qf[(1 * 64 + l) * 8];
        bf16x8 al0 = *(bf16x8*)&qf[(2 * 64 + l) * 8];
        bf16x8 al1 = *(bf16x8*)&qf[(3 * 64 + l) * 8];

        for (int i = 0; i < 16; ++i) {
            int kt = w + (i << 3);          // this wave's k-tile (16 keys)
            int k0 = kt << 4;
            f32x4 acc = {0.f, 0.f, 0.f, 0.f};
            size_t off0 = ((size_t)((bh * 2 + 0) * S_LEN + k0 + l15) << 5) + lg * 8;
            size_t off1 = ((size_t)((bh * 2 + 1) * S_LEN + k0 + l15) << 5) + lg * 8;
            bf16x8 kh0 = *(const bf16x8*)(kh + off0);
            bf16x8 kl0 = *(const bf16x8*)(kl + off0);
            bf16x8 kh1 = *(const bf16x8*)(kh + off1);
            bf16x8 kl1 = *(const bf16x8*)(kl + off1);
            acc = __builtin_amdgcn_mfma_f32_16x16x32_bf16(ah0, kh0, acc, 0, 0, 0);
            acc = __builtin_amdgcn_mfma_f32_16x16x32_bf16(al0, kh0, acc, 0, 0, 0);
            acc = __builtin_amdgcn_mfma_f32_16x16x32_bf16(ah0, kl0, acc, 0, 0, 0);
            acc = __builtin_amdgcn_mfma_f32_16x16x32_bf16(ah1, kh1, acc, 0, 0, 0);
            acc = __builtin_amdgcn_mfma_f32_16x16x32_bf16(al1, kh1, acc, 0, 0, 0);
            acc = __builtin_amdgcn_mfma_f32_16x16x32_bf16(ah1, kl1, acc, 0, 0, 0);

            // C layout (verified): col = k0 + l15, row = lg*4 + r
            int col  = k0 + l15;
            int c    = col >> 5;
            int gcol = (col >> 3) & 3;
            int j    = col & 7;
            // idx = c*512 + ((gcol<<4)|(r<<2)|lg)*8 + j  -> base + r*32
            int base = (c << 9) + (((gcol << 4) | lg) << 3) + j;
            lds[base +  0] = acc[0];
            lds[base + 32] = acc[1];
            lds[base + 64] = acc[2];
            lds[base + 96] = acc[3];
        }
    }
    __syncthreads();

    // ---- P2: per-row max (over raw scores; shift-invariant) ----------------
    {
        float mx = -3.0e38f;
        for (int cc = 0; cc < 8; ++cc) {
            int c = (w << 3) + cc;
            int base = (c << 9) + (alane << 3);
            f32x4 v1 = *(f32x4*)&lds[base];
            f32x4 v2 = *(f32x4*)&lds[base + 4];
            mx = fmaxf(mx, fmaxf(fmaxf(v1[0], v1[1]), fmaxf(v1[2], v1[3])));
            mx = fmaxf(mx, fmaxf(fmaxf(v2[0], v2[1]), fmaxf(v2[2], v2[3])));
        }
        mx = fmaxf(mx, __shfl_xor(mx, 16, 64));
        mx = fmaxf(mx, __shfl_xor(mx, 32, 64));
        if (l < 16) pmax[(w << 4) + l] = mx;
    }
    __syncthreads();
    if (t < 16) {
        float m = pmax[t];
        for (int ww = 1; ww < 8; ++ww) m = fmaxf(m, pmax[(ww << 4) + t]);
        mrow[t] = m;
    }
    __syncthreads();

    // ---- P3: e = mask ? 0 : exp(s - m); write back; row sums ---------------
    {
        const int* mbase = mask + (size_t)bh * S_LEN * S_LEN
                                + (size_t)(q0 + l15) * S_LEN;
        float m = mrow[l15];
        float sum = 0.f;
        for (int cc = 0; cc < 8; ++cc) {
            int c = (w << 3) + cc;
            int base = (c << 9) + (alane << 3);
            int colb = (c << 5) + (lg << 3);
            f32x4 v1 = *(f32x4*)&lds[base];
            f32x4 v2 = *(f32x4*)&lds[base + 4];
            int4 m1 = *(const int4*)(mbase + colb);
            int4 m2 = *(const int4*)(mbase + colb + 4);
            f32x4 e1, e2;
            e1[0] = m1.x ? 0.f : __expf(v1[0] - m);
            e1[1] = m1.y ? 0.f : __expf(v1[1] - m);
            e1[2] = m1.z ? 0.f : __expf(v1[2] - m);
            e1[3] = m1.w ? 0.f : __expf(v1[3] - m);
            e2[0] = m2.x ? 0.f : __expf(v2[0] - m);
            e2[1] = m2.y ? 0.f : __expf(v2[1] - m);
            e2[2] = m2.z ? 0.f : __expf(v2[2] - m);
            e2[3] = m2.w ? 0.f : __expf(v2[3] - m);
            *(f32x4*)&lds[base]     = e1;
            *(f32x4*)&lds[base + 4] = e2;
            sum += e1[0] + e1[1] + e1[2] + e1[3]
                 + e2[0] + e2[1] + e2[2] + e2[3];
        }
        sum += __shfl_xor(sum, 16, 64);
        sum += __shfl_xor(sum, 32, 64);
        if (l < 16) psum[(w << 4) + l] = sum;
    }
    __syncthreads();
    if (t < 16) {
        float s = 0.f;
        for (int ww = 0; ww < 8; ++ww) s += psum[(ww << 4) + t];
        rinv[t] = 1.0f / s;
    }
    __syncthreads();

    // ---- P4: write p = e * rinv to global; PV MFMA on e --------------------
    {
        float rv = rinv[l15];
        float* sbase = scoresOut + (size_t)bh * S_LEN * S_LEN
                                 + (size_t)(q0 + l15) * S_LEN;
        for (int cc = 0; cc < 8; ++cc) {
            int c = (w << 3) + cc;
            int base = (c << 9) + (alane << 3);
            int colb = (c << 5) + (lg << 3);
            f32x4 v1 = *(f32x4*)&lds[base];
            f32x4 v2 = *(f32x4*)&lds[base + 4];
            v1 *= rv;
            v2 *= rv;
            *(f32x4*)(sbase + colb)     = v1;
            *(f32x4*)(sbase + colb + 4) = v2;
        }

        // PV: wave w -> n-tile (w&3), k-half (w>>2). 32 chunks of K=32.
        int n0    = (w & 3) << 4;
        int khalf = w >> 2;
        f32x4 acc = {0.f, 0.f, 0.f, 0.f};
        const __bf16* vbase = vb + ((size_t)(bh * 64 + n0 + l15) << 11) + lg * 8;
        for (int cc = 0; cc < 32; ++cc) {
            int c = (khalf << 5) + cc;
            int base = (c << 9) + (alane << 3);
            f32x4 v1 = *(f32x4*)&lds[base];
            f32x4 v2 = *(f32x4*)&lds[base + 4];
            bf16x8 pa;
            pa[0] = (__bf16)v1[0]; pa[1] = (__bf16)v1[1];
            pa[2] = (__bf16)v1[2]; pa[3] = (__bf16)v1[3];
            pa[4] = (__bf16)v2[0]; pa[5] = (__bf16)v2[1];
            pa[6] = (__bf16)v2[2]; pa[7] = (__bf16)v2[3];
            bf16x8 bv = *(const bf16x8*)(vbase + ((size_t)c << 5));
            acc = __builtin_amdgcn_mfma_f32_16x16x32_bf16(pa, bv, acc, 0, 0, 0);
        }
        // partials[w][row][col]: row = lg*4 + r, col = l15
        int pbase = (w << 8) + (lg << 6) + l15;
        parts[pbase +  0] = acc[0];
        parts[pbase + 16] = acc[1];
        parts[pbase + 32] = acc[2];
        parts[pbase + 48] = acc[3];
    }
    __syncthreads();

    // ---- P5: reduce k-halves, scale by rinv, write context -----------------
    {
        float* cbase = ctxOut + ((size_t)bh * S_LEN + q0) * 64;
        for (int e = t; e < 1024; e += 512) {
            int row = e >> 6, d = e & 63;
            int nt = d >> 4, ii = d & 15;
            float v = (parts[(nt << 8) + (row << 4) + ii] +
                       parts[((nt + 4) << 8) + (row << 4) + ii]) * rinv[row];
            cbase[e] = v;
        }
    }
}

extern "C" void kernel_launch(void* const* d_in, const int* in_sizes, int n_in,
                              void* d_out, int out_size, void* d_ws, size_t ws_size,
                              hipStream_t stream) {
    const float* Q    = (const float*)d_in[0];
    const float* K    = (const float*)d_in[1];
    const float* V    = (const float*)d_in[2];
    const int*   mask = (const int*)d_in[3];

    float* ctxOut    = (float*)d_out;                 // [2,16,2048,64]
    float* scoresOut = ctxOut + (size_t)NBH * S_LEN * 64;  // [2,16,2048,2048]

    __bf16* kh = (__bf16*)d_ws;                       // 4,194,304 bf16
    __bf16* kl = kh + (size_t)NBH * S_LEN * 64;
    __bf16* vb = kl + (size_t)NBH * S_LEN * 64;       // total ws use: 25.2 MB

    prep_k<<<4096, 256, 0, stream>>>(K, kh, kl);
    prep_v<<<4096, 256, 0, stream>>>(V, vb);

    const int lds_bytes = 36128 * 4;  // 144512
    hipFuncSetAttribute((const void*)attn_kernel,
                        hipFuncAttributeMaxDynamicSharedMemorySize, lds_bytes);

    dim3 grid(S_LEN / 16, NBH);
    attn_kernel<<<grid, 512, lds_bytes, stream>>>(Q, mask, kh, kl, vb,
                                                  ctxOut, scoresOut);
}

// Round 2
// 1169.708 us; speedup vs baseline: 1.1798x; 1.1798x over previous
//
#include <hip/hip_runtime.h>

#define S_LEN 2048
#define NBH   32   // B*H = 2*16

typedef __attribute__((ext_vector_type(8))) __bf16 bf16x8;
typedef __attribute__((ext_vector_type(4))) float  f32x4;

// ---------------------------------------------------------------------------
// prep_k: K fp32 -> (kh, kl) bf16 hi/lo, fragment layout:
//   element (bh, key, d): dc=d>>5, g=(d>>3)&3, j=d&7
//   off = ((bh*2+dc)*2048 + key)*32 + g*8 + j
// ---------------------------------------------------------------------------
__global__ __launch_bounds__(256) void prep_k(const float* __restrict__ K,
                                              __bf16* __restrict__ kh,
                                              __bf16* __restrict__ kl) {
    const int total = NBH * S_LEN * 64;
    for (int idx = blockIdx.x * 256 + threadIdx.x; idx < total;
         idx += gridDim.x * 256) {
        int d   = idx & 63;
        int key = (idx >> 6) & (S_LEN - 1);
        int bh  = idx >> 17;
        float f = K[idx];
        __bf16 h  = (__bf16)f;
        __bf16 lo = (__bf16)(f - (float)h);
        int dc = d >> 5, g = (d >> 3) & 3, j = d & 7;
        size_t off = ((size_t)((bh * 2 + dc) * S_LEN + key) << 5) + g * 8 + j;
        kh[off] = h;
        kl[off] = lo;
    }
}

// ---------------------------------------------------------------------------
// prep_v: V fp32 -> vb bf16, transposed fragment layout:
//   element (bh, k, n): kc=k>>5, g=(k>>3)&3, j=k&7
//   off = ((bh*64+n)*64 + kc)*32 + g*8 + j
// ---------------------------------------------------------------------------
__global__ __launch_bounds__(256) void prep_v(const float* __restrict__ V,
                                              __bf16* __restrict__ vb) {
    const int total = NBH * S_LEN * 64;
    for (int idx = blockIdx.x * 256 + threadIdx.x; idx < total;
         idx += gridDim.x * 256) {
        int n  = idx & 63;
        int k  = (idx >> 6) & (S_LEN - 1);
        int bh = idx >> 17;
        float f = V[idx];
        int kc = k >> 5, g = (k >> 3) & 3, j = k & 7;
        size_t off = ((size_t)((bh * 64 + n) * 64 + kc) << 5) + g * 8 + j;
        vb[off] = (__bf16)f;
    }
}

// ---------------------------------------------------------------------------
// Main kernel, v2: scores live in registers (f32x4 acc[16] per lane, C-layout).
// LDS holds only: e as bf16 (for PV A-fragment transpose), Q fragments, and
// small reduction buffers. 77.1 KB -> 2 blocks/CU, 16 waves/CU.
//
// LDS f32 map (19744 f32 = 78976 B):
//   [0,16384)       eb: 32768 bf16, e values. Logical (row,col):
//                   c=col>>5, gc=(col>>3)&3, j=col&7, L=(gc<<4)|((row&3)<<2)|(row>>2)
//                   phys bf16 idx = c*512 + (L ^ (L>>4 & 3))*8 + j
//                   (XOR spreads the b16 scatter stores; b128 reads stay free)
//   [16384,17408)   qf: [2 prec][2 dc][64 lane][8] bf16
//   [17408,17536)   pmax[8][16]
//   [17536,17664)   psum[8][16]
//   [17664,17680)   mrow[16]
//   [17680,17696)   rinv[16]
//   [17696,19744)   parts[8][16][16]
// ---------------------------------------------------------------------------
__global__ __launch_bounds__(512, 4) void attn_kernel(
    const float* __restrict__ Q, const int* __restrict__ mask,
    const __bf16* __restrict__ kh, const __bf16* __restrict__ kl,
    const __bf16* __restrict__ vb,
    float* __restrict__ ctxOut, float* __restrict__ scoresOut)
{
    extern __shared__ float lds[];
    __bf16* eb   = (__bf16*)lds;
    __bf16* qf   = (__bf16*)(lds + 16384);
    float*  pmax = lds + 17408;
    float*  psum = lds + 17536;
    float*  mrow = lds + 17664;
    float*  rinv = lds + 17680;
    float*  parts= lds + 17696;

    const int t   = threadIdx.x;
    const int w   = t >> 6;
    const int l   = t & 63;
    const int l15 = l & 15;
    const int lg  = l >> 4;
    const int bh  = blockIdx.y;
    const int q0  = blockIdx.x << 4;

    // ---- P0: stage Q*scale as hi/lo bf16 A-fragments -----------------------
    {
        const float* Qg = Q + ((size_t)bh * S_LEN + q0) * 64;
        #pragma unroll
        for (int e = t; e < 16 * 64; e += 512) {
            int row = e >> 6, d = e & 63;
            float fs = Qg[e] * 0.125f;                 // fold 1/sqrt(64)
            __bf16 h  = (__bf16)fs;
            __bf16 lo = (__bf16)(fs - (float)h);
            int dc = d >> 5, g = (d >> 3) & 3, j = d & 7;
            int lane2 = (g << 4) | row;
            qf[((0 + dc) * 64 + lane2) * 8 + j] = h;
            qf[((2 + dc) * 64 + lane2) * 8 + j] = lo;
        }
    }
    __syncthreads();

    // ---- P1: QK^T via split bf16 MFMA; scores stay in registers ------------
    f32x4 acc[16];
    {
        bf16x8 ah0 = *(bf16x8*)&qf[(0 * 64 + l) * 8];
        bf16x8 ah1 = *(bf16x8*)&qf[(1 * 64 + l) * 8];
        bf16x8 al0 = *(bf16x8*)&qf[(2 * 64 + l) * 8];
        bf16x8 al1 = *(bf16x8*)&qf[(3 * 64 + l) * 8];

        #pragma unroll
        for (int i = 0; i < 16; ++i) {
            int kt = w + (i << 3);          // this wave's k-tile (16 keys)
            int k0 = kt << 4;
            f32x4 a = {0.f, 0.f, 0.f, 0.f};
            size_t off0 = ((size_t)((bh * 2 + 0) * S_LEN + k0 + l15) << 5) + lg * 8;
            size_t off1 = ((size_t)((bh * 2 + 1) * S_LEN + k0 + l15) << 5) + lg * 8;
            bf16x8 kh0 = *(const bf16x8*)(kh + off0);
            bf16x8 kl0 = *(const bf16x8*)(kl + off0);
            bf16x8 kh1 = *(const bf16x8*)(kh + off1);
            bf16x8 kl1 = *(const bf16x8*)(kl + off1);
            a = __builtin_amdgcn_mfma_f32_16x16x32_bf16(ah0, kh0, a, 0, 0, 0);
            a = __builtin_amdgcn_mfma_f32_16x16x32_bf16(al0, kh0, a, 0, 0, 0);
            a = __builtin_amdgcn_mfma_f32_16x16x32_bf16(ah0, kl0, a, 0, 0, 0);
            a = __builtin_amdgcn_mfma_f32_16x16x32_bf16(ah1, kh1, a, 0, 0, 0);
            a = __builtin_amdgcn_mfma_f32_16x16x32_bf16(al1, kh1, a, 0, 0, 0);
            a = __builtin_amdgcn_mfma_f32_16x16x32_bf16(ah1, kl1, a, 0, 0, 0);
            acc[i] = a;
        }
    }

    // ---- P2: per-row max from registers (rows lg*4+r, shift-invariant) -----
    {
        f32x4 mx = acc[0];
        #pragma unroll
        for (int i = 1; i < 16; ++i) {
            mx[0] = fmaxf(mx[0], acc[i][0]);
            mx[1] = fmaxf(mx[1], acc[i][1]);
            mx[2] = fmaxf(mx[2], acc[i][2]);
            mx[3] = fmaxf(mx[3], acc[i][3]);
        }
        #pragma unroll
        for (int r = 0; r < 4; ++r) {
            float v = mx[r];
            v = fmaxf(v, __shfl_xor(v, 1, 64));
            v = fmaxf(v, __shfl_xor(v, 2, 64));
            v = fmaxf(v, __shfl_xor(v, 4, 64));
            v = fmaxf(v, __shfl_xor(v, 8, 64));
            if (l15 == 0) pmax[(w << 4) + (lg << 2) + r] = v;
        }
    }
    __syncthreads();
    if (t < 16) {
        float m = pmax[t];
        for (int ww = 1; ww < 8; ++ww) m = fmaxf(m, pmax[(ww << 4) + t]);
        mrow[t] = m;
    }
    __syncthreads();

    // ---- P3: e = mask ? 0 : exp(s-m); keep in regs; e->LDS bf16; row sums --
    {
        float mr0 = mrow[(lg << 2) + 0];
        float mr1 = mrow[(lg << 2) + 1];
        float mr2 = mrow[(lg << 2) + 2];
        float mr3 = mrow[(lg << 2) + 3];
        const int* mb = mask + (size_t)bh * S_LEN * S_LEN
                             + (size_t)(q0 + (lg << 2)) * S_LEN + l15;
        f32x4 sum = {0.f, 0.f, 0.f, 0.f};
        #pragma unroll
        for (int i = 0; i < 16; ++i) {
            int kt = w + (i << 3);
            int k0 = kt << 4;
            // eb store base: c=kt>>1, gc=((kt&1)<<1)|(l15>>3), lg'=lg^gc, j=l15&7
            int gc = ((kt & 1) << 1) | (l15 >> 3);
            int ebase = ((kt >> 1) << 9) | (gc << 7) | ((lg ^ gc) << 3) | (l15 & 7);
            int m0 = mb[(size_t)0 * S_LEN + k0];
            int m1 = mb[(size_t)1 * S_LEN + k0];
            int m2 = mb[(size_t)2 * S_LEN + k0];
            int m3 = mb[(size_t)3 * S_LEN + k0];
            float e0 = m0 ? 0.f : __expf(acc[i][0] - mr0);
            float e1 = m1 ? 0.f : __expf(acc[i][1] - mr1);
            float e2 = m2 ? 0.f : __expf(acc[i][2] - mr2);
            float e3 = m3 ? 0.f : __expf(acc[i][3] - mr3);
            acc[i][0] = e0; acc[i][1] = e1; acc[i][2] = e2; acc[i][3] = e3;
            sum[0] += e0; sum[1] += e1; sum[2] += e2; sum[3] += e3;
            eb[ebase +  0] = (__bf16)e0;
            eb[ebase + 32] = (__bf16)e1;
            eb[ebase + 64] = (__bf16)e2;
            eb[ebase + 96] = (__bf16)e3;
        }
        #pragma unroll
        for (int r = 0; r < 4; ++r) {
            float v = sum[r];
            v += __shfl_xor(v, 1, 64);
            v += __shfl_xor(v, 2, 64);
            v += __shfl_xor(v, 4, 64);
            v += __shfl_xor(v, 8, 64);
            if (l15 == 0) psum[(w << 4) + (lg << 2) + r] = v;
        }
    }
    __syncthreads();
    if (t < 16) {
        float s = 0.f;
        for (int ww = 0; ww < 8; ++ww) s += psum[(ww << 4) + t];
        rinv[t] = 1.0f / s;
    }
    __syncthreads();

    // ---- P4a: p = e * rinv -> global (from registers, coalesced 64B rows) --
    {
        float rv0 = rinv[(lg << 2) + 0];
        float rv1 = rinv[(lg << 2) + 1];
        float rv2 = rinv[(lg << 2) + 2];
        float rv3 = rinv[(lg << 2) + 3];
        float* sb = scoresOut + (size_t)bh * S_LEN * S_LEN
                              + (size_t)(q0 + (lg << 2)) * S_LEN + l15;
        #pragma unroll
        for (int i = 0; i < 16; ++i) {
            int k0 = (w + (i << 3)) << 4;
            sb[(size_t)0 * S_LEN + k0] = acc[i][0] * rv0;
            sb[(size_t)1 * S_LEN + k0] = acc[i][1] * rv1;
            sb[(size_t)2 * S_LEN + k0] = acc[i][2] * rv2;
            sb[(size_t)3 * S_LEN + k0] = acc[i][3] * rv3;
        }
    }

    // ---- P4b: PV MFMA from eb (bf16, conflict-free b128 reads) -------------
    {
        int n0    = (w & 3) << 4;
        int khalf = w >> 2;
        // A-fragment lane slot with the same XOR the store used:
        const int alane  = (lg << 4) | ((l15 & 3) << 2) | (l15 >> 2);
        const int alane2 = alane ^ lg;   // (alane>>4)&3 == lg
        f32x4 o = {0.f, 0.f, 0.f, 0.f};
        const __bf16* vbase = vb + ((size_t)(bh * 64 + n0 + l15) << 11) + lg * 8;
        #pragma unroll
        for (int cc = 0; cc < 32; ++cc) {
            int c = (khalf << 5) + cc;
            bf16x8 pa = *(bf16x8*)&eb[(c << 9) + (alane2 << 3)];
            bf16x8 bv = *(const bf16x8*)(vbase + ((size_t)c << 5));
            o = __builtin_amdgcn_mfma_f32_16x16x32_bf16(pa, bv, o, 0, 0, 0);
        }
        // partials[w][row][col]: row = lg*4 + r, col = l15
        int pbase = (w << 8) + (lg << 6) + l15;
        parts[pbase +  0] = o[0];
        parts[pbase + 16] = o[1];
        parts[pbase + 32] = o[2];
        parts[pbase + 48] = o[3];
    }
    __syncthreads();

    // ---- P5: reduce k-halves, scale by rinv, write context -----------------
    {
        float* cbase = ctxOut + ((size_t)bh * S_LEN + q0) * 64;
        #pragma unroll
        for (int e = t; e < 1024; e += 512) {
            int row = e >> 6, d = e & 63;
            int nt = d >> 4, ii = d & 15;
            float v = (parts[(nt << 8) + (row << 4) + ii] +
                       parts[((nt + 4) << 8) + (row << 4) + ii]) * rinv[row];
            cbase[e] = v;
        }
    }
}

extern "C" void kernel_launch(void* const* d_in, const int* in_sizes, int n_in,
                              void* d_out, int out_size, void* d_ws, size_t ws_size,
                              hipStream_t stream) {
    const float* Q    = (const float*)d_in[0];
    const float* K    = (const float*)d_in[1];
    const float* V    = (const float*)d_in[2];
    const int*   mask = (const int*)d_in[3];

    float* ctxOut    = (float*)d_out;                      // [2,16,2048,64]
    float* scoresOut = ctxOut + (size_t)NBH * S_LEN * 64;  // [2,16,2048,2048]

    __bf16* kh = (__bf16*)d_ws;
    __bf16* kl = kh + (size_t)NBH * S_LEN * 64;
    __bf16* vb = kl + (size_t)NBH * S_LEN * 64;            // ws use: 25.2 MB

    prep_k<<<4096, 256, 0, stream>>>(K, kh, kl);
    prep_v<<<4096, 256, 0, stream>>>(V, vb);

    const int lds_bytes = 19744 * 4;  // 78976 B -> 2 blocks/CU
    hipFuncSetAttribute((const void*)attn_kernel,
                        hipFuncAttributeMaxDynamicSharedMemorySize, lds_bytes);

    dim3 grid(S_LEN / 16, NBH);
    attn_kernel<<<grid, 512, lds_bytes, stream>>>(Q, mask, kh, kl, vb,
                                                  ctxOut, scoresOut);
}